// Round 4
// baseline (573.103 us; speedup 1.0000x reference)
//
#include <hip/hip_runtime.h>
#include <hip/hip_bf16.h>

typedef __attribute__((ext_vector_type(4))) float f32x4;
typedef __attribute__((ext_vector_type(8))) short bf8;
typedef __attribute__((ext_vector_type(2))) int i32x2;

#define B_ 2
#define ST 2048
#define SC 1024
#define SK 3072
#define NH 16
#define DH 128
#define KVB 64
#define NT (SK / KVB)     // 48 tiles
#define TGT (ST / KVB)    // 32 target tiles
#define SCALE 0.088388347648318447f

__device__ __forceinline__ unsigned short f2bf(float f) {
    union { __hip_bfloat16 b; unsigned short u; } c;
    c.b = __float2bfloat16(f);
    return c.u;
}

__device__ __forceinline__ i32x2 tr_read(unsigned a) {
    i32x2 d;
    asm volatile("ds_read_b64_tr_b16 %0, %1" : "=v"(d) : "v"(a));
    return d;
}

__device__ __forceinline__ bf8 mk_bf8(i32x2 a, i32x2 b) {
    union { i32x2 h[2]; bf8 v; } u;
    u.h[0] = a; u.h[1] = b;
    return u.v;
}

__device__ __forceinline__ bf8 pack_bf8(f32x4 a, f32x4 b) {
    bf8 v;
    v[0]=(short)f2bf(a[0]); v[1]=(short)f2bf(a[1]);
    v[2]=(short)f2bf(a[2]); v[3]=(short)f2bf(a[3]);
    v[4]=(short)f2bf(b[0]); v[5]=(short)f2bf(b[1]);
    v[6]=(short)f2bf(b[2]); v[7]=(short)f2bf(b[3]);
    return v;
}

// DPP lane-swap within 16-lane rows (VALU-speed, no LDS latency)
template<int CTRL>
__device__ __forceinline__ float dpp_f(float x) {
    union { float f; int i; } u, r;
    u.f = x;
    r.i = __builtin_amdgcn_update_dpp(u.i, u.i, CTRL, 0xf, 0xf, false);
    return r.f;
}
// 16-lane all-reduce: xor1 (quad_perm 0xB1), xor2 (0x4E), fold quads
// (row_half_mirror 0x141), fold octets (row_mirror 0x140)
__device__ __forceinline__ float red16_max(float x) {
    x = fmaxf(x, dpp_f<0xB1>(x));
    x = fmaxf(x, dpp_f<0x4E>(x));
    x = fmaxf(x, dpp_f<0x141>(x));
    x = fmaxf(x, dpp_f<0x140>(x));
    return x;
}
__device__ __forceinline__ float red16_sum(float x) {
    x += dpp_f<0xB1>(x);
    x += dpp_f<0x4E>(x);
    x += dpp_f<0x141>(x);
    x += dpp_f<0x140>(x);
    return x;
}

__global__ __launch_bounds__(512, 4)
void attn_fwd(const float* __restrict__ Q,
              const float* __restrict__ TK,
              const float* __restrict__ TV,
              const float* __restrict__ CK,
              const float* __restrict__ CV,
              const float* __restrict__ BP,
              float* __restrict__ OUT)
{
    // K: logical [64][128] bf16 XOR-swizzled (byte ^= (row&7)<<4); LINEAR
    //    ds_write, swizzle folded into global source column.
    // V: s21 layout byte(k,d) = (k>>5)*8192 + (d>>4)*1024 + (k&31)*32 + (d&15)*2
    //    (subtiles [32 k][16 d]; wave's 4 group-tiles at 256 B steps). LINEAR
    //    write: chunk c -> vrow=(c>>9)*32+((c>>1)&31), vcol=((c>>6)&7)*16+(c&1)*8.
    // Pt: per-wave P transposed [kv=64][q=16] bf16.
    __shared__ __align__(16) unsigned short Ks[2][KVB * DH];
    __shared__ __align__(16) unsigned short Vs[2][KVB * DH];
    __shared__ __align__(16) unsigned short Pt[8][KVB * 16];

    const int tid = threadIdx.x;
    const int w   = tid >> 6;          // 0..7
    const int l   = tid & 63;
    const int l15 = l & 15;
    const int g   = l >> 4;

    // XCD-aware mapping: 512 blocks; each bh's 16 q-tiles stay on one XCD.
    const int bid = blockIdx.x;
    const int xcd = bid & 7;
    const int sub = bid >> 3;          // 0..63
    const int bh  = xcd * 4 + (sub >> 4);
    const int qt  = sub & 15;          // 0..15 (128-row q tiles)
    const int bb  = bh >> 4;
    const int hh  = bh & 15;

    const float bias_c = BP[0];

    // ---- Q fragments (A-layout), pre-scaled ----
    const int qrow = qt * 128 + w * 16 + l15;
    const float* qp = Q + (((size_t)bb * ST + qrow) * NH + hh) * DH;
    bf8 qf[4];
#pragma unroll
    for (int kc = 0; kc < 4; ++kc) {
        const f32x4 x0 = *(const f32x4*)(qp + kc * 32 + g * 8);
        const f32x4 x1 = *(const f32x4*)(qp + kc * 32 + g * 8 + 4);
        bf8 v;
        v[0]=(short)f2bf(x0[0]*SCALE); v[1]=(short)f2bf(x0[1]*SCALE);
        v[2]=(short)f2bf(x0[2]*SCALE); v[3]=(short)f2bf(x0[3]*SCALE);
        v[4]=(short)f2bf(x1[0]*SCALE); v[5]=(short)f2bf(x1[1]*SCALE);
        v[6]=(short)f2bf(x1[2]*SCALE); v[7]=(short)f2bf(x1[3]*SCALE);
        qf[kc] = v;
    }

    f32x4 oa[8];
#pragma unroll
    for (int i = 0; i < 8; ++i) oa[i] = (f32x4){0.f, 0.f, 0.f, 0.f};
    float mrow[4] = {-1e30f, -1e30f, -1e30f, -1e30f};
    float lrow[4] = {0.f, 0.f, 0.f, 0.f};

    // staging registers (T14 async-STAGE: issue-early / write-late)
    f32x4 skr[2][2], svr[2][2];

    const unsigned vsBase = (unsigned)(size_t)&Vs[0][0];
    const unsigned ptBase = (unsigned)(size_t)&Pt[0][0];
    const unsigned vA0 = vsBase + (unsigned)(g * 256 + l15 * 8);
    const unsigned pA  = ptBase + (unsigned)(w * 2048 + g * 256 + l15 * 8);

    auto stage_load = [&](int t) {
        const int kv0 = t * KVB;
        const float *kb, *vb;
        if (kv0 < ST) {
            const size_t off = (((size_t)bb * ST + kv0) * NH + hh) * DH;
            kb = TK + off; vb = TV + off;
        } else {
            const size_t off = (((size_t)bb * SC + (kv0 - ST)) * NH + hh) * DH;
            kb = CK + off; vb = CV + off;
        }
#pragma unroll
        for (int i = 0; i < 2; ++i) {
            const int c = tid + (i << 9);          // 0..1023
            const int krow = c >> 4;
            const int kcol = ((c & 15) ^ (krow & 7)) << 3;
            const float* kp = kb + (size_t)krow * (NH * DH) + kcol;
            skr[i][0] = *(const f32x4*)kp;
            skr[i][1] = *(const f32x4*)(kp + 4);
            const int vrow = ((c >> 9) << 5) | ((c >> 1) & 31);
            const int vcol = (((c >> 6) & 7) << 4) | ((c & 1) << 3);
            const float* vp = vb + (size_t)vrow * (NH * DH) + vcol;
            svr[i][0] = *(const f32x4*)vp;
            svr[i][1] = *(const f32x4*)(vp + 4);
        }
    };

    auto stage_write = [&](int buf) {
#pragma unroll
        for (int i = 0; i < 2; ++i) {
            const int c = tid + (i << 9);
            *(bf8*)((char*)Ks[buf] + c * 16) = pack_bf8(skr[i][0], skr[i][1]);
            *(bf8*)((char*)Vs[buf] + c * 16) = pack_bf8(svr[i][0], svr[i][1]);
        }
    };

    stage_load(0);
    stage_write(0);

    for (int t = 0; t < NT; ++t) {
        __syncthreads();                 // buf[t&1] visible; other buf free
        if (t + 1 < NT) stage_load(t + 1);   // issue loads, write at end
        const int buf = t & 1;
        const float bias = (t >= TGT) ? bias_c : 0.f;

        // ---- QK^T: S[16 q][64 kv] as four 16-col n-tiles ----
        f32x4 s[4];
#pragma unroll
        for (int nt = 0; nt < 4; ++nt) s[nt] = (f32x4){0.f, 0.f, 0.f, 0.f};
        __builtin_amdgcn_s_setprio(1);
#pragma unroll
        for (int kc = 0; kc < 4; ++kc) {
            const int cb = (kc * 32 + g * 8) * 2;
#pragma unroll
            for (int nt = 0; nt < 4; ++nt) {
                const int r = nt * 16 + l15;
                int o = r * 256 + cb;
                o ^= (r & 7) << 4;
                const bf8 kf = *(const bf8*)((const char*)Ks[buf] + o);
                s[nt] = __builtin_amdgcn_mfma_f32_16x16x32_bf16(qf[kc], kf, s[nt], 0, 0, 0);
            }
        }
        __builtin_amdgcn_s_setprio(0);

        // ---- online softmax (DPP reductions), defer-max THR=8 ----
        float mx4[4];
        bool need = false;
#pragma unroll
        for (int r = 0; r < 4; ++r) {
            float mx = fmaxf(fmaxf(s[0][r], s[1][r]), fmaxf(s[2][r], s[3][r]));
            mx = red16_max(mx);
            mx4[r] = mx + bias;
            need = need || (mx4[r] > mrow[r] + 8.f);
        }
        if (__any(need)) {
#pragma unroll
            for (int r = 0; r < 4; ++r) {
                const float mnew = fmaxf(mrow[r], mx4[r]);
                const float corr = __expf(mrow[r] - mnew);
                mrow[r] = mnew;
                lrow[r] *= corr;
#pragma unroll
                for (int dc = 0; dc < 8; ++dc) oa[dc][r] *= corr;
            }
        }
        float pp[4][4];   // [nt][r]
#pragma unroll
        for (int r = 0; r < 4; ++r) {
            const float zb = bias - mrow[r];
            float rs = 0.f;
#pragma unroll
            for (int nt = 0; nt < 4; ++nt) {
                const float p = __expf(s[nt][r] + zb);
                pp[nt][r] = p;
                rs += p;
            }
            lrow[r] += red16_sum(rs);
        }
        // ---- pack P -> Pt (transposed [kv][q]) ----
        char* ptw = (char*)Pt[w] + l15 * 32 + g * 8;
#pragma unroll
        for (int nt = 0; nt < 4; ++nt) {
            const unsigned lo = (unsigned)f2bf(pp[nt][0]) | ((unsigned)f2bf(pp[nt][1]) << 16);
            const unsigned hi = (unsigned)f2bf(pp[nt][2]) | ((unsigned)f2bf(pp[nt][3]) << 16);
            i32x2 d2; d2[0] = (int)lo; d2[1] = (int)hi;
            *(i32x2*)(ptw + nt * 512) = d2;
        }

        // ---- PV via HW transpose reads, per-kr clusters ----
        asm volatile("" ::: "memory");     // order Pt stores before tr-reads
        const unsigned vA = vA0 + (unsigned)(buf << 14);
#pragma unroll
        for (int kr = 0; kr < 2; ++kr) {
            const unsigned pa = pA + kr * 1024;
            i32x2 p0 = tr_read(pa);
            i32x2 p1 = tr_read(pa + 128);
            const unsigned vb = vA + kr * 8192;
            i32x2 vt_[8][2];
#pragma unroll
            for (int dc = 0; dc < 8; ++dc) {
                vt_[dc][0] = tr_read(vb + dc * 1024);
                vt_[dc][1] = tr_read(vb + dc * 1024 + 128);
            }
            asm volatile("s_waitcnt lgkmcnt(0)");
            __builtin_amdgcn_sched_barrier(0);
            __builtin_amdgcn_s_setprio(1);
            const bf8 pf = mk_bf8(p0, p1);
#pragma unroll
            for (int dc = 0; dc < 8; ++dc) {
                const bf8 vf = mk_bf8(vt_[dc][0], vt_[dc][1]);
                oa[dc] = __builtin_amdgcn_mfma_f32_16x16x32_bf16(pf, vf, oa[dc], 0, 0, 0);
            }
            __builtin_amdgcn_s_setprio(0);
        }

        // ---- write-late: next tile's staged regs -> LDS ----
        if (t + 1 < NT) stage_write(buf ^ 1);
    }

    // ---- epilogue: normalize and store fp32 ----
    float* op = OUT + (((size_t)bb * ST + qt * 128 + w * 16) * NH + hh) * DH;
#pragma unroll
    for (int r = 0; r < 4; ++r) {
        const float inv = 1.0f / lrow[r];
        float* rp = op + (size_t)(g * 4 + r) * (NH * DH);
#pragma unroll
        for (int dc = 0; dc < 8; ++dc)
            rp[dc * 16 + l15] = oa[dc][r] * inv;
    }
}

extern "C" void kernel_launch(void* const* d_in, const int* in_sizes, int n_in,
                              void* d_out, int out_size, void* d_ws, size_t ws_size,
                              hipStream_t stream) {
    const float* q  = (const float*)d_in[0];
    const float* tk = (const float*)d_in[1];
    const float* tv = (const float*)d_in[2];
    const float* ck = (const float*)d_in[3];
    const float* cv = (const float*)d_in[4];
    const float* bp = (const float*)d_in[5];
    float* out = (float*)d_out;
    attn_fwd<<<dim3((ST / 128) * B_ * NH), 512, 0, stream>>>(q, tk, tv, ck, cv, bp, out);
}

// Round 5
// 362.604 us; speedup vs baseline: 1.5805x; 1.5805x over previous
//
#include <hip/hip_runtime.h>
#include <hip/hip_bf16.h>

typedef __attribute__((ext_vector_type(4))) float f32x4;
typedef __attribute__((ext_vector_type(8))) short bf8;
typedef __attribute__((ext_vector_type(2))) int i32x2;

#define B_ 2
#define ST 2048
#define SC 1024
#define SK 3072
#define NH 16
#define DH 128
#define KVB 64
#define NT (SK / KVB)     // 48 tiles
#define TGT (ST / KVB)    // 32 target tiles
#define SCALE 0.088388347648318447f

__device__ __forceinline__ unsigned short f2bf(float f) {
    union { __hip_bfloat16 b; unsigned short u; } c;
    c.b = __float2bfloat16(f);
    return c.u;
}

__device__ __forceinline__ i32x2 tr_read(unsigned a) {
    i32x2 d;
    asm volatile("ds_read_b64_tr_b16 %0, %1" : "=v"(d) : "v"(a));
    return d;
}

__device__ __forceinline__ bf8 mk_bf8(i32x2 a, i32x2 b) {
    union { i32x2 h[2]; bf8 v; } u;
    u.h[0] = a; u.h[1] = b;
    return u.v;
}

__device__ __forceinline__ bf8 pack_bf8(f32x4 a, f32x4 b) {
    bf8 v;
    v[0]=(short)f2bf(a[0]); v[1]=(short)f2bf(a[1]);
    v[2]=(short)f2bf(a[2]); v[3]=(short)f2bf(a[3]);
    v[4]=(short)f2bf(b[0]); v[5]=(short)f2bf(b[1]);
    v[6]=(short)f2bf(b[2]); v[7]=(short)f2bf(b[3]);
    return v;
}

// DPP 16-lane all-reduce (VALU-speed, no LDS)
template<int CTRL>
__device__ __forceinline__ float dpp_f(float x) {
    union { float f; int i; } u, r;
    u.f = x;
    r.i = __builtin_amdgcn_update_dpp(u.i, u.i, CTRL, 0xf, 0xf, false);
    return r.f;
}
__device__ __forceinline__ float red16_max(float x) {
    x = fmaxf(x, dpp_f<0xB1>(x));
    x = fmaxf(x, dpp_f<0x4E>(x));
    x = fmaxf(x, dpp_f<0x141>(x));
    x = fmaxf(x, dpp_f<0x140>(x));
    return x;
}
__device__ __forceinline__ float red16_sum(float x) {
    x += dpp_f<0xB1>(x);
    x += dpp_f<0x4E>(x);
    x += dpp_f<0x141>(x);
    x += dpp_f<0x140>(x);
    return x;
}

__global__ __launch_bounds__(256, 2)
void attn_fwd(const float* __restrict__ Q,
              const float* __restrict__ TK,
              const float* __restrict__ TV,
              const float* __restrict__ CK,
              const float* __restrict__ CV,
              const float* __restrict__ BP,
              float* __restrict__ OUT)
{
    // 4 waves x 32 q-rows (2 MFMA subtiles) = 128 q-rows per block.
    // K: [64][128] bf16 XOR-swizzled (byte ^= (row&7)<<4); LINEAR ds_write,
    //    swizzle folded into global source column.
    // V: [k/4][d/16][4][16] subtiles for ds_read_b64_tr_b16; LINEAR write.
    // Pt: per wave x qs: P transposed [kv=64][q=16] bf16.
    __shared__ __align__(16) unsigned short Ks[2][KVB * DH];   // 32 KB
    __shared__ __align__(16) unsigned short Vs[2][KVB * DH];   // 32 KB
    __shared__ __align__(16) unsigned short Pt[8][KVB * 16];   // 16 KB

    const int tid = threadIdx.x;
    const int w   = tid >> 6;
    const int l   = tid & 63;
    const int l15 = l & 15;
    const int g   = l >> 4;

    // XCD-aware mapping: 512 blocks = 8 XCD x 4 bh x 16 q-tiles.
    const int bid = blockIdx.x;
    const int xcd = bid & 7;
    const int sub = bid >> 3;          // 0..63
    const int bh  = xcd * 4 + (sub >> 4);
    const int qt  = sub & 15;          // 128-row q tiles
    const int bb  = bh >> 4;
    const int hh  = bh & 15;

    const float bias_c = BP[0];

    // ---- Q fragments (A-layout), 2 subtiles, pre-scaled ----
    bf8 qf[2][4];
#pragma unroll
    for (int qs = 0; qs < 2; ++qs) {
        const int qrow = qt * 128 + w * 32 + qs * 16 + l15;
        const float* qp = Q + (((size_t)bb * ST + qrow) * NH + hh) * DH;
#pragma unroll
        for (int kc = 0; kc < 4; ++kc) {
            const f32x4 x0 = *(const f32x4*)(qp + kc * 32 + g * 8);
            const f32x4 x1 = *(const f32x4*)(qp + kc * 32 + g * 8 + 4);
            bf8 v;
            v[0]=(short)f2bf(x0[0]*SCALE); v[1]=(short)f2bf(x0[1]*SCALE);
            v[2]=(short)f2bf(x0[2]*SCALE); v[3]=(short)f2bf(x0[3]*SCALE);
            v[4]=(short)f2bf(x1[0]*SCALE); v[5]=(short)f2bf(x1[1]*SCALE);
            v[6]=(short)f2bf(x1[2]*SCALE); v[7]=(short)f2bf(x1[3]*SCALE);
            qf[qs][kc] = v;
        }
    }

    f32x4 oa[2][8];
#pragma unroll
    for (int qs = 0; qs < 2; ++qs)
#pragma unroll
        for (int i = 0; i < 8; ++i) oa[qs][i] = (f32x4){0.f, 0.f, 0.f, 0.f};
    float mrow[2][4], lrow[2][4];
#pragma unroll
    for (int qs = 0; qs < 2; ++qs)
#pragma unroll
        for (int r = 0; r < 4; ++r) { mrow[qs][r] = -1e30f; lrow[qs][r] = 0.f; }

    // staging registers (T14 async-STAGE: issue-early / write-late)
    f32x4 skr[4][2], svr[4][2];

    const unsigned vsBase = (unsigned)(size_t)&Vs[0][0];
    const unsigned ptBase = (unsigned)(size_t)&Pt[0][0];
    const unsigned vA0 = vsBase + (unsigned)(g * 2048 + l15 * 8);
    const unsigned pA  = ptBase + (unsigned)(w * 4096 + g * 256 + l15 * 8);

    auto stage_load = [&](int t) {
        const int kv0 = t * KVB;
        const float *kb, *vb;
        if (kv0 < ST) {
            const size_t off = (((size_t)bb * ST + kv0) * NH + hh) * DH;
            kb = TK + off; vb = TV + off;
        } else {
            const size_t off = (((size_t)bb * SC + (kv0 - ST)) * NH + hh) * DH;
            kb = CK + off; vb = CV + off;
        }
#pragma unroll
        for (int i = 0; i < 4; ++i) {
            const int c = tid + (i << 8);          // 0..1023
            const int krow = c >> 4;
            const int kcol = ((c & 15) ^ (krow & 7)) << 3;
            const float* kp = kb + (size_t)krow * (NH * DH) + kcol;
            skr[i][0] = *(const f32x4*)kp;
            skr[i][1] = *(const f32x4*)(kp + 4);
            const int vrow = ((c >> 6) << 2) | ((c >> 1) & 3);
            const int vcol = (((c >> 3) & 7) << 4) | ((c & 1) << 3);
            const float* vp = vb + (size_t)vrow * (NH * DH) + vcol;
            svr[i][0] = *(const f32x4*)vp;
            svr[i][1] = *(const f32x4*)(vp + 4);
        }
    };

    auto stage_write = [&](int buf) {
#pragma unroll
        for (int i = 0; i < 4; ++i) {
            const int c = tid + (i << 8);
            *(bf8*)((char*)Ks[buf] + c * 16) = pack_bf8(skr[i][0], skr[i][1]);
            *(bf8*)((char*)Vs[buf] + c * 16) = pack_bf8(svr[i][0], svr[i][1]);
        }
    };

    stage_load(0);
    stage_write(0);

    for (int t = 0; t < NT; ++t) {
        __syncthreads();                 // buf[t&1] visible; other buf free
        if (t + 1 < NT) stage_load(t + 1);   // issue loads, write at end
        const int buf = t & 1;
        const float bias = (t >= TGT) ? bias_c : 0.f;

        // ---- QK^T: S[32 q][64 kv]; each K fragment feeds 2 MFMAs ----
        f32x4 s[2][4];
#pragma unroll
        for (int qs = 0; qs < 2; ++qs)
#pragma unroll
            for (int nt = 0; nt < 4; ++nt) s[qs][nt] = (f32x4){0.f, 0.f, 0.f, 0.f};
        __builtin_amdgcn_s_setprio(1);
#pragma unroll
        for (int kc = 0; kc < 4; ++kc) {
            const int cb = (kc * 32 + g * 8) * 2;
#pragma unroll
            for (int nt = 0; nt < 4; ++nt) {
                const int r = nt * 16 + l15;
                int o = r * 256 + cb;
                o ^= (r & 7) << 4;
                const bf8 kf = *(const bf8*)((const char*)Ks[buf] + o);
                s[0][nt] = __builtin_amdgcn_mfma_f32_16x16x32_bf16(qf[0][kc], kf, s[0][nt], 0, 0, 0);
                s[1][nt] = __builtin_amdgcn_mfma_f32_16x16x32_bf16(qf[1][kc], kf, s[1][nt], 0, 0, 0);
            }
        }
        __builtin_amdgcn_s_setprio(0);

        // ---- online softmax (DPP reductions), defer-max THR=8 ----
        float mx4[2][4];
        bool need = false;
#pragma unroll
        for (int qs = 0; qs < 2; ++qs)
#pragma unroll
            for (int r = 0; r < 4; ++r) {
                float mx = fmaxf(fmaxf(s[qs][0][r], s[qs][1][r]),
                                 fmaxf(s[qs][2][r], s[qs][3][r]));
                mx = red16_max(mx);
                mx4[qs][r] = mx + bias;
                need = need || (mx4[qs][r] > mrow[qs][r] + 8.f);
            }
        if (__any(need)) {
#pragma unroll
            for (int qs = 0; qs < 2; ++qs)
#pragma unroll
                for (int r = 0; r < 4; ++r) {
                    const float mnew = fmaxf(mrow[qs][r], mx4[qs][r]);
                    const float corr = __expf(mrow[qs][r] - mnew);
                    mrow[qs][r] = mnew;
                    lrow[qs][r] *= corr;
#pragma unroll
                    for (int dc = 0; dc < 8; ++dc) oa[qs][dc][r] *= corr;
                }
        }
#pragma unroll
        for (int qs = 0; qs < 2; ++qs) {
            float pp[4][4];   // [nt][r]
#pragma unroll
            for (int r = 0; r < 4; ++r) {
                const float zb = bias - mrow[qs][r];
                float rs = 0.f;
#pragma unroll
                for (int nt = 0; nt < 4; ++nt) {
                    const float p = __expf(s[qs][nt][r] + zb);
                    pp[nt][r] = p;
                    rs += p;
                }
                lrow[qs][r] += red16_sum(rs);
            }
            // pack P -> Pt (transposed [kv][q])
            char* ptw = (char*)Pt[0] + w * 4096 + qs * 2048 + l15 * 32 + g * 8;
#pragma unroll
            for (int nt = 0; nt < 4; ++nt) {
                const unsigned lo = (unsigned)f2bf(pp[nt][0]) | ((unsigned)f2bf(pp[nt][1]) << 16);
                const unsigned hi = (unsigned)f2bf(pp[nt][2]) | ((unsigned)f2bf(pp[nt][3]) << 16);
                i32x2 d2; d2[0] = (int)lo; d2[1] = (int)hi;
                *(i32x2*)(ptw + nt * 512) = d2;
            }
        }

        // ---- PV via HW transpose reads; V reads shared across 2 q-subtiles ----
        asm volatile("" ::: "memory");     // order Pt stores before tr-reads
        const unsigned vA = vA0 + (unsigned)(buf << 14);
#pragma unroll
        for (int kr = 0; kr < 2; ++kr) {
            const unsigned pa = pA + kr * 1024;
            i32x2 p00 = tr_read(pa);
            i32x2 p01 = tr_read(pa + 128);
            i32x2 p10 = tr_read(pa + 2048);
            i32x2 p11 = tr_read(pa + 2048 + 128);
            const unsigned vb = vA + kr * 8192;
            i32x2 vt_[8][2];
#pragma unroll
            for (int dc = 0; dc < 8; ++dc) {
                vt_[dc][0] = tr_read(vb + dc * 128);
                vt_[dc][1] = tr_read(vb + dc * 128 + 1024);
            }
            asm volatile("s_waitcnt lgkmcnt(0)");
            __builtin_amdgcn_sched_barrier(0);
            __builtin_amdgcn_s_setprio(1);
            const bf8 pf0 = mk_bf8(p00, p01);
            const bf8 pf1 = mk_bf8(p10, p11);
#pragma unroll
            for (int dc = 0; dc < 8; ++dc) {
                const bf8 vf = mk_bf8(vt_[dc][0], vt_[dc][1]);
                oa[0][dc] = __builtin_amdgcn_mfma_f32_16x16x32_bf16(pf0, vf, oa[0][dc], 0, 0, 0);
                oa[1][dc] = __builtin_amdgcn_mfma_f32_16x16x32_bf16(pf1, vf, oa[1][dc], 0, 0, 0);
            }
            __builtin_amdgcn_s_setprio(0);
        }

        // ---- write-late: next tile's staged regs -> LDS ----
        if (t + 1 < NT) stage_write(buf ^ 1);
    }

    // ---- epilogue: normalize and store fp32 ----
#pragma unroll
    for (int qs = 0; qs < 2; ++qs) {
        float* op = OUT + (((size_t)bb * ST + qt * 128 + w * 32 + qs * 16) * NH + hh) * DH;
#pragma unroll
        for (int r = 0; r < 4; ++r) {
            const float inv = 1.0f / lrow[qs][r];
            float* rp = op + (size_t)(g * 4 + r) * (NH * DH);
#pragma unroll
            for (int dc = 0; dc < 8; ++dc)
                rp[dc * 16 + l15] = oa[qs][dc][r] * inv;
        }
    }
}

extern "C" void kernel_launch(void* const* d_in, const int* in_sizes, int n_in,
                              void* d_out, int out_size, void* d_ws, size_t ws_size,
                              hipStream_t stream) {
    const float* q  = (const float*)d_in[0];
    const float* tk = (const float*)d_in[1];
    const float* tv = (const float*)d_in[2];
    const float* ck = (const float*)d_in[3];
    const float* cv = (const float*)d_in[4];
    const float* bp = (const float*)d_in[5];
    float* out = (float*)d_out;
    attn_fwd<<<dim3((ST / 128) * B_ * NH), 256, 0, stream>>>(q, tk, tv, ck, cv, bp, out);
}

// Round 7
// 154.608 us; speedup vs baseline: 3.7068x; 2.3453x over previous
//
#include <hip/hip_runtime.h>
#include <hip/hip_bf16.h>

typedef __attribute__((ext_vector_type(4))) float f32x4;
typedef __attribute__((ext_vector_type(16))) float f32x16;
typedef __attribute__((ext_vector_type(8))) short bf8;
typedef __attribute__((ext_vector_type(2))) int i32x2;

#define B_ 2
#define ST 2048
#define SC 1024
#define SK 3072
#define NH 16
#define DH 128
#define KVB 32
#define NT 96
#define TGT 64
#define SCALE 0.088388347648318447f

__device__ __forceinline__ unsigned short f2bf(float f) {
    union { __hip_bfloat16 b; unsigned short u; } c;
    c.b = __float2bfloat16(f);
    return c.u;
}

__device__ __forceinline__ i32x2 tr_read(unsigned a) {
    i32x2 d;
    asm volatile("ds_read_b64_tr_b16 %0, %1" : "=v"(d) : "v"(a));
    return d;
}

__device__ __forceinline__ unsigned cvtpk(float lo, float hi) {
    unsigned r;
    asm("v_cvt_pk_bf16_f32 %0, %1, %2" : "=v"(r) : "v"(lo), "v"(hi));
    return r;
}

// v_permlane32_swap_b32 a,b : a.hi32lanes <-> b.lo32lanes (distinct values only!)
__device__ __forceinline__ void swap32(unsigned &a, unsigned &b) {
    asm volatile("v_permlane32_swap_b32 %0, %1" : "+v"(a), "+v"(b));
}
// cross-half reduce via ds_bpermute (guaranteed distinct-register semantics)
__device__ __forceinline__ float xmax32(float x) {
    return fmaxf(x, __shfl_xor(x, 32));
}
__device__ __forceinline__ float xsum32(float x) {
    return x + __shfl_xor(x, 32);
}

__device__ __forceinline__ bf8 pack_bf8(f32x4 a, f32x4 b) {
    bf8 v;
    v[0]=(short)f2bf(a[0]); v[1]=(short)f2bf(a[1]);
    v[2]=(short)f2bf(a[2]); v[3]=(short)f2bf(a[3]);
    v[4]=(short)f2bf(b[0]); v[5]=(short)f2bf(b[1]);
    v[6]=(short)f2bf(b[2]); v[7]=(short)f2bf(b[3]);
    return v;
}

__device__ __forceinline__ bf8 mk_bf8(i32x2 a, i32x2 b) {
    union { i32x2 h[2]; bf8 v; } u;
    u.h[0] = a; u.h[1] = b;
    return u.v;
}
__device__ __forceinline__ bf8 mk_bf8w(unsigned w0, unsigned w1, unsigned w2, unsigned w3) {
    union { unsigned w[4]; bf8 v; } u;
    u.w[0] = w0; u.w[1] = w1; u.w[2] = w2; u.w[3] = w3;
    return u.v;
}

__global__ __launch_bounds__(256, 2)
void attn_fwd(const float* __restrict__ Q,
              const float* __restrict__ TK,
              const float* __restrict__ TV,
              const float* __restrict__ CK,
              const float* __restrict__ CV,
              const float* __restrict__ BP,
              float* __restrict__ OUT)
{
    // 4 waves x 32 q-rows = 128 q-rows/block. Swapped QK^T and PV:
    //   S^T[kv][q] = mfma(A=K[kv][d], B=Q^T[d][q])   (q = lane&31 everywhere)
    //   O^T[d][q]  = mfma(A=V^T[d][kv], B=P[kv][q])
    // K: [32][128] bf16, XOR-swizzled (byte ^= (row&7)<<4), LINEAR ds_write
    //    with swizzle folded into global source column.
    // V: tile-permuted layout for ds_read_b64_tr_b16 A-fragments:
    //    byte(kv,d) = slot*128 + (kv&3)*32 + (d&15)*2,
    //    slot = ks*32 + kbi*16 + dt*4 + hi*2 + dbl  where
    //    kv = 16ks+8hi+4kbi+(kv&3), d = 32dt+16dbl+(d&15).
    __shared__ __align__(16) unsigned short Ks[2][KVB * DH];   // 2 x 8 KB
    __shared__ __align__(16) unsigned short Vs[2][KVB * DH];   // 2 x 8 KB

    const int tid = threadIdx.x;
    const int w   = tid >> 6;
    const int l   = tid & 63;
    const int r31 = l & 31;            // = q for B/C operands, = kv row for K A-op
    const int hi  = l >> 5;

    // XCD-aware mapping: 512 blocks = 8 XCD x 4 bh x 16 q-tiles
    const int bid = blockIdx.x;
    const int xcd = bid & 7;
    const int sub = bid >> 3;
    const int bh  = xcd * 4 + (sub >> 4);
    const int qt  = sub & 15;
    const int bb  = bh >> 4;
    const int hh  = bh & 15;

    const float bias_c = BP[0];

    // ---- Q fragments (B-operand): lane holds Q[q=r31][d=16dk+8hi+j], scaled ----
    const int qrow = qt * 128 + w * 32 + r31;
    const float* qp = Q + (((size_t)bb * ST + qrow) * NH + hh) * DH;
    bf8 qf[8];
#pragma unroll
    for (int dk = 0; dk < 8; ++dk) {
        const f32x4 x0 = *(const f32x4*)(qp + dk * 16 + hi * 8);
        const f32x4 x1 = *(const f32x4*)(qp + dk * 16 + hi * 8 + 4);
        bf8 v;
        v[0]=(short)f2bf(x0[0]*SCALE); v[1]=(short)f2bf(x0[1]*SCALE);
        v[2]=(short)f2bf(x0[2]*SCALE); v[3]=(short)f2bf(x0[3]*SCALE);
        v[4]=(short)f2bf(x1[0]*SCALE); v[5]=(short)f2bf(x1[1]*SCALE);
        v[6]=(short)f2bf(x1[2]*SCALE); v[7]=(short)f2bf(x1[3]*SCALE);
        qf[dk] = v;
    }

    f32x16 oa[4];
#pragma unroll
    for (int dt = 0; dt < 4; ++dt)
#pragma unroll
        for (int e = 0; e < 16; ++e) oa[dt][e] = 0.f;
    float m_run = -1e30f, l_run = 0.f;

    // staging registers (issue-early / write-late)
    f32x4 skr[2][2], svr[2][2];

    auto stage_load = [&](int t) {
        const int kv0 = t * KVB;
        const float *kb, *vb;
        if (kv0 < ST) {
            const size_t off = (((size_t)bb * ST + kv0) * NH + hh) * DH;
            kb = TK + off; vb = TV + off;
        } else {
            const size_t off = (((size_t)bb * SC + (kv0 - ST)) * NH + hh) * DH;
            kb = CK + off; vb = CV + off;
        }
#pragma unroll
        for (int i = 0; i < 2; ++i) {
            const int c = tid + (i << 8);          // 0..511 16B chunks
            const int krow = c >> 4;               // 0..31
            const int kcol = ((c & 15) ^ (krow & 7)) << 3;
            const float* kp = kb + (size_t)krow * (NH * DH) + kcol;
            skr[i][0] = *(const f32x4*)kp;
            skr[i][1] = *(const f32x4*)(kp + 4);
            const int vkv = (((c >> 8) & 1) << 4) | (((c >> 4) & 1) << 3)
                          | (((c >> 7) & 1) << 2) | ((c >> 1) & 3);
            const int vd  = (((c >> 5) & 3) << 5) | (((c >> 3) & 1) << 4)
                          | ((c & 1) << 3);
            const float* vp = vb + (size_t)vkv * (NH * DH) + vd;
            svr[i][0] = *(const f32x4*)vp;
            svr[i][1] = *(const f32x4*)(vp + 4);
        }
    };

    auto stage_write = [&](int buf) {
#pragma unroll
        for (int i = 0; i < 2; ++i) {
            const int c = tid + (i << 8);
            *(bf8*)((char*)Ks[buf] + c * 16) = pack_bf8(skr[i][0], skr[i][1]);
            *(bf8*)((char*)Vs[buf] + c * 16) = pack_bf8(svr[i][0], svr[i][1]);
        }
    };

    stage_load(0);
    stage_write(0);

    const unsigned vLane = (unsigned)(size_t)&Vs[0][0] + (unsigned)((l >> 4) * 128 + (l & 15) * 8);

    for (int t = 0; t < NT; ++t) {
        __syncthreads();
        if (t + 1 < NT) stage_load(t + 1);
        const int buf = t & 1;
        const float bias = (t >= TGT) ? bias_c : 0.f;

        // ---- QK^T swapped: S^T[kv=crow(e,hi)][q=r31], two interleaved accs ----
        f32x16 s0, s1;
#pragma unroll
        for (int e = 0; e < 16; ++e) { s0[e] = 0.f; s1[e] = 0.f; }
        __builtin_amdgcn_s_setprio(1);
#pragma unroll
        for (int dk = 0; dk < 8; dk += 2) {
            int o0 = r31 * 256 + (dk * 16 + hi * 8) * 2;
            o0 ^= (r31 & 7) << 4;
            const bf8 kf0 = *(const bf8*)((const char*)Ks[buf] + o0);
            s0 = __builtin_amdgcn_mfma_f32_32x32x16_bf16(kf0, qf[dk], s0, 0, 0, 0);
            int o1 = r31 * 256 + ((dk + 1) * 16 + hi * 8) * 2;
            o1 ^= (r31 & 7) << 4;
            const bf8 kf1 = *(const bf8*)((const char*)Ks[buf] + o1);
            s1 = __builtin_amdgcn_mfma_f32_32x32x16_bf16(kf1, qf[dk + 1], s1, 0, 0, 0);
        }
        __builtin_amdgcn_s_setprio(0);
        float p[16];
#pragma unroll
        for (int e = 0; e < 16; ++e) p[e] = s0[e] + s1[e];

        // ---- in-register online softmax (lane-local q), defer-max THR=8 ----
        float mx = p[0];
#pragma unroll
        for (int e = 1; e < 16; ++e) mx = fmaxf(mx, p[e]);
        mx = xmax32(mx) + bias;
        const int need = (mx > m_run + 8.f) ? 1 : 0;
        if (__any(need)) {
            const float mnew = fmaxf(m_run, mx);
            const float corr = __expf(m_run - mnew);
            m_run = mnew;
            l_run *= corr;
#pragma unroll
            for (int dt = 0; dt < 4; ++dt)
#pragma unroll
                for (int e = 0; e < 16; ++e) oa[dt][e] *= corr;
        }
        const float zb = bias - m_run;
        float rs = 0.f;
#pragma unroll
        for (int e = 0; e < 16; ++e) { p[e] = __expf(p[e] + zb); rs += p[e]; }
        l_run += xsum32(rs);

        // ---- pack P (C-layout) -> B-operand fragments via cvt_pk + permlane ----
        unsigned a0 = cvtpk(p[0], p[1]),  b0 = cvtpk(p[4], p[5]);
        unsigned a1 = cvtpk(p[2], p[3]),  b1 = cvtpk(p[6], p[7]);
        swap32(a0, b0); swap32(a1, b1);
        const bf8 pf0 = mk_bf8w(a0, a1, b0, b1);
        unsigned a2 = cvtpk(p[8], p[9]),   b2 = cvtpk(p[12], p[13]);
        unsigned a3 = cvtpk(p[10], p[11]), b3 = cvtpk(p[14], p[15]);
        swap32(a2, b2); swap32(a3, b3);
        const bf8 pf1 = mk_bf8w(a2, a3, b2, b3);

        // ---- PV swapped: O^T[d][q] += V^T x P, per-ks clusters ----
        const unsigned vA = vLane + (unsigned)(buf << 13);
#pragma unroll
        for (int ks = 0; ks < 2; ++ks) {
            const unsigned vk = vA + (unsigned)(ks << 12);
            i32x2 vt_[4][2];
#pragma unroll
            for (int dt = 0; dt < 4; ++dt) {
                vt_[dt][0] = tr_read(vk + dt * 512);
                vt_[dt][1] = tr_read(vk + dt * 512 + 2048);
            }
            asm volatile("s_waitcnt lgkmcnt(0)");
            __builtin_amdgcn_sched_barrier(0);
            __builtin_amdgcn_s_setprio(1);
            const bf8 pf = ks ? pf1 : pf0;
#pragma unroll
            for (int dt = 0; dt < 4; ++dt) {
                const bf8 vf = mk_bf8(vt_[dt][0], vt_[dt][1]);
                oa[dt] = __builtin_amdgcn_mfma_f32_32x32x16_bf16(vf, pf, oa[dt], 0, 0, 0);
            }
            __builtin_amdgcn_s_setprio(0);
        }

        // ---- write-late: next tile's staged regs -> LDS ----
        if (t + 1 < NT) stage_write(buf ^ 1);
    }

    // ---- epilogue: normalize, store fp32; lane owns q=r31, d=32dt+8rr+4hi+i ----
    const float inv = 1.0f / l_run;
    float* op = OUT + ((size_t)(bb * ST + qrow)) * (NH * DH) + hh * DH;
#pragma unroll
    for (int dt = 0; dt < 4; ++dt)
#pragma unroll
        for (int rr = 0; rr < 4; ++rr) {
            f32x4 st;
            st[0] = oa[dt][rr * 4 + 0] * inv;
            st[1] = oa[dt][rr * 4 + 1] * inv;
            st[2] = oa[dt][rr * 4 + 2] * inv;
            st[3] = oa[dt][rr * 4 + 3] * inv;
            *(f32x4*)(op + dt * 32 + rr * 8 + hi * 4) = st;
        }
}

extern "C" void kernel_launch(void* const* d_in, const int* in_sizes, int n_in,
                              void* d_out, int out_size, void* d_ws, size_t ws_size,
                              hipStream_t stream) {
    const float* q  = (const float*)d_in[0];
    const float* tk = (const float*)d_in[1];
    const float* tv = (const float*)d_in[2];
    const float* ck = (const float*)d_in[3];
    const float* cv = (const float*)d_in[4];
    const float* bp = (const float*)d_in[5];
    float* out = (float*)d_out;
    attn_fwd<<<dim3((ST / 128) * B_ * NH), 256, 0, stream>>>(q, tk, tv, ck, cv, bp, out);
}

// Round 9
// 153.451 us; speedup vs baseline: 3.7348x; 1.0075x over previous
//
#include <hip/hip_runtime.h>
#include <hip/hip_bf16.h>

typedef __attribute__((ext_vector_type(4))) float f32x4;
typedef __attribute__((ext_vector_type(16))) float f32x16;
typedef __attribute__((ext_vector_type(8))) short bf8;
typedef __attribute__((ext_vector_type(2))) int i32x2;

#define B_ 2
#define ST 2048
#define SC 1024
#define SK 3072
#define NH 16
#define DH 128
#define KVB 32
#define NT 96
#define TGT 64
#define SCALE 0.088388347648318447f

__device__ __forceinline__ unsigned short f2bf(float f) {
    union { __hip_bfloat16 b; unsigned short u; } c;
    c.b = __float2bfloat16(f);
    return c.u;
}

__device__ __forceinline__ i32x2 tr_read(unsigned a) {
    i32x2 d;
    asm volatile("ds_read_b64_tr_b16 %0, %1" : "=v"(d) : "v"(a));
    return d;
}

__device__ __forceinline__ unsigned cvtpk(float lo, float hi) {
    unsigned r;
    asm("v_cvt_pk_bf16_f32 %0, %1, %2" : "=v"(r) : "v"(lo), "v"(hi));
    return r;
}

// v_permlane32_swap_b32 a,b : a.hi32lanes <-> b.lo32lanes.
// PROVEN SAFE only with two independently-computed values (P-pack below, R7).
// PROVEN BROKEN as a copy-then-swap self-reduce (R6: 0.137, R8: 0.136) —
// use ds_bpermute (__shfl_xor) for cross-half reductions.
__device__ __forceinline__ void swap32(unsigned &a, unsigned &b) {
    asm volatile("v_permlane32_swap_b32 %0, %1" : "+v"(a), "+v"(b));
}
__device__ __forceinline__ float xmax32(float x) {
    return fmaxf(x, __shfl_xor(x, 32));
}
__device__ __forceinline__ float xsum32(float x) {
    return x + __shfl_xor(x, 32);
}

__device__ __forceinline__ bf8 pack_bf8(f32x4 a, f32x4 b) {
    bf8 v;
    v[0]=(short)f2bf(a[0]); v[1]=(short)f2bf(a[1]);
    v[2]=(short)f2bf(a[2]); v[3]=(short)f2bf(a[3]);
    v[4]=(short)f2bf(b[0]); v[5]=(short)f2bf(b[1]);
    v[6]=(short)f2bf(b[2]); v[7]=(short)f2bf(b[3]);
    return v;
}

__device__ __forceinline__ bf8 mk_bf8(i32x2 a, i32x2 b) {
    union { i32x2 h[2]; bf8 v; } u;
    u.h[0] = a; u.h[1] = b;
    return u.v;
}
__device__ __forceinline__ bf8 mk_bf8w(unsigned w0, unsigned w1, unsigned w2, unsigned w3) {
    union { unsigned w[4]; bf8 v; } u;
    u.w[0] = w0; u.w[1] = w1; u.w[2] = w2; u.w[3] = w3;
    return u.v;
}

__global__ __launch_bounds__(256, 2)
void attn_fwd(const float* __restrict__ Q,
              const float* __restrict__ TK,
              const float* __restrict__ TV,
              const float* __restrict__ CK,
              const float* __restrict__ CV,
              const float* __restrict__ BP,
              float* __restrict__ OUT)
{
    // 4 waves x 32 q-rows = 128 q-rows/block. Swapped QK^T and PV:
    //   S^T[kv][q] = mfma(A=K[kv][d], B=Q^T[d][q])   (q = lane&31 everywhere)
    //   O^T[d][q]  = mfma(A=V^T[d][kv], B=P[kv][q])
    // K: [32][128] bf16, XOR-swizzled (byte ^= (row&7)<<4), LINEAR ds_write
    //    with swizzle folded into global source column.
    // V: tile-permuted layout for ds_read_b64_tr_b16 A-fragments (verified R7);
    //    LINEAR ds_write, permutation folded into global source address.
    __shared__ __align__(16) unsigned short Ks[2][KVB * DH];   // 2 x 8 KB
    __shared__ __align__(16) unsigned short Vs[2][KVB * DH];   // 2 x 8 KB

    const int tid = threadIdx.x;
    const int w   = tid >> 6;
    const int l   = tid & 63;
    const int r31 = l & 31;            // = q for B/C operands, = kv row for K A-op
    const int hi  = l >> 5;

    // XCD-aware mapping: 512 blocks = 8 XCD x 4 bh x 16 q-tiles
    const int bid = blockIdx.x;
    const int xcd = bid & 7;
    const int sub = bid >> 3;
    const int bh  = xcd * 4 + (sub >> 4);
    const int qt  = sub & 15;
    const int bb  = bh >> 4;
    const int hh  = bh & 15;

    const float bias_c = BP[0];

    // ---- Q fragments (B-operand): lane holds Q[q=r31][d=16dk+8hi+j], scaled ----
    const int qrow = qt * 128 + w * 32 + r31;
    const float* qp = Q + (((size_t)bb * ST + qrow) * NH + hh) * DH;
    bf8 qf[8];
#pragma unroll
    for (int dk = 0; dk < 8; ++dk) {
        const f32x4 x0 = *(const f32x4*)(qp + dk * 16 + hi * 8);
        const f32x4 x1 = *(const f32x4*)(qp + dk * 16 + hi * 8 + 4);
        bf8 v;
        v[0]=(short)f2bf(x0[0]*SCALE); v[1]=(short)f2bf(x0[1]*SCALE);
        v[2]=(short)f2bf(x0[2]*SCALE); v[3]=(short)f2bf(x0[3]*SCALE);
        v[4]=(short)f2bf(x1[0]*SCALE); v[5]=(short)f2bf(x1[1]*SCALE);
        v[6]=(short)f2bf(x1[2]*SCALE); v[7]=(short)f2bf(x1[3]*SCALE);
        qf[dk] = v;
    }

    f32x16 oa[4];
#pragma unroll
    for (int dt = 0; dt < 4; ++dt)
#pragma unroll
        for (int e = 0; e < 16; ++e) oa[dt][e] = 0.f;
    float m_run = -1e30f, l_run = 0.f;

    // staging registers (issue-early / write-late)
    f32x4 skr[2][2], svr[2][2];

    auto stage_load = [&](int t) {
        const int kv0 = t * KVB;
        const float *kb, *vb;
        if (kv0 < ST) {
            const size_t off = (((size_t)bb * ST + kv0) * NH + hh) * DH;
            kb = TK + off; vb = TV + off;
        } else {
            const size_t off = (((size_t)bb * SC + (kv0 - ST)) * NH + hh) * DH;
            kb = CK + off; vb = CV + off;
        }
#pragma unroll
        for (int i = 0; i < 2; ++i) {
            const int c = tid + (i << 8);          // 0..511 16B chunks
            const int krow = c >> 4;               // 0..31
            const int kcol = ((c & 15) ^ (krow & 7)) << 3;
            const float* kp = kb + (size_t)krow * (NH * DH) + kcol;
            skr[i][0] = *(const f32x4*)kp;
            skr[i][1] = *(const f32x4*)(kp + 4);
            const int vkv = (((c >> 8) & 1) << 4) | (((c >> 4) & 1) << 3)
                          | (((c >> 7) & 1) << 2) | ((c >> 1) & 3);
            const int vd  = (((c >> 5) & 3) << 5) | (((c >> 3) & 1) << 4)
                          | ((c & 1) << 3);
            const float* vp = vb + (size_t)vkv * (NH * DH) + vd;
            svr[i][0] = *(const f32x4*)vp;
            svr[i][1] = *(const f32x4*)(vp + 4);
        }
    };

    auto stage_write = [&](int buf) {
#pragma unroll
        for (int i = 0; i < 2; ++i) {
            const int c = tid + (i << 8);
            *(bf8*)((char*)Ks[buf] + c * 16) = pack_bf8(skr[i][0], skr[i][1]);
            *(bf8*)((char*)Vs[buf] + c * 16) = pack_bf8(svr[i][0], svr[i][1]);
        }
    };

    stage_load(0);
    stage_write(0);

    const unsigned vLane = (unsigned)(size_t)&Vs[0][0] + (unsigned)((l >> 4) * 128 + (l & 15) * 8);

    for (int t = 0; t < NT; ++t) {
        __syncthreads();
        if (t + 1 < NT) stage_load(t + 1);
        const int buf = t & 1;
        const float bias = (t >= TGT) ? bias_c : 0.f;

        // ---- QK^T swapped: S^T[kv=crow(e,hi)][q=r31], two interleaved accs ----
        f32x16 s0, s1;
#pragma unroll
        for (int e = 0; e < 16; ++e) { s0[e] = 0.f; s1[e] = 0.f; }
        __builtin_amdgcn_s_setprio(1);
#pragma unroll
        for (int dk = 0; dk < 8; dk += 2) {
            int o0 = r31 * 256 + (dk * 16 + hi * 8) * 2;
            o0 ^= (r31 & 7) << 4;
            const bf8 kf0 = *(const bf8*)((const char*)Ks[buf] + o0);
            s0 = __builtin_amdgcn_mfma_f32_32x32x16_bf16(kf0, qf[dk], s0, 0, 0, 0);
            int o1 = r31 * 256 + ((dk + 1) * 16 + hi * 8) * 2;
            o1 ^= (r31 & 7) << 4;
            const bf8 kf1 = *(const bf8*)((const char*)Ks[buf] + o1);
            s1 = __builtin_amdgcn_mfma_f32_32x32x16_bf16(kf1, qf[dk + 1], s1, 0, 0, 0);
        }
        __builtin_amdgcn_s_setprio(0);

        // ---- issue ALL V tr-reads now; latency hides under softmax (VALU) ----
        asm volatile("" ::: "memory");     // keep K ds_reads above, tr-reads here
        const unsigned vA = vLane + (unsigned)(buf << 13);
        i32x2 vt_[2][4][2];
#pragma unroll
        for (int ks = 0; ks < 2; ++ks) {
            const unsigned vk = vA + (unsigned)(ks << 12);
#pragma unroll
            for (int dt = 0; dt < 4; ++dt) {
                vt_[ks][dt][0] = tr_read(vk + dt * 512);
                vt_[ks][dt][1] = tr_read(vk + dt * 512 + 2048);
            }
        }

        float p[16];
#pragma unroll
        for (int e = 0; e < 16; ++e) p[e] = s0[e] + s1[e];

        // ---- in-register online softmax (lane-local q), defer-max THR=8 ----
        float mx = p[0];
#pragma unroll
        for (int e = 1; e < 16; ++e) mx = fmaxf(mx, p[e]);
        mx = xmax32(mx) + bias;
        const int need = (mx > m_run + 8.f) ? 1 : 0;
        if (__any(need)) {
            const float mnew = fmaxf(m_run, mx);
            const float corr = __expf(m_run - mnew);
            m_run = mnew;
            l_run *= corr;
#pragma unroll
            for (int dt = 0; dt < 4; ++dt)
#pragma unroll
                for (int e = 0; e < 16; ++e) oa[dt][e] *= corr;
        }
        const float zb = bias - m_run;
        float rs = 0.f;
#pragma unroll
        for (int e = 0; e < 16; ++e) { p[e] = __expf(p[e] + zb); rs += p[e]; }
        l_run += xsum32(rs);

        // ---- pack P (C-layout) -> B-operand fragments via cvt_pk + permlane ----
        unsigned a0 = cvtpk(p[0], p[1]),  b0 = cvtpk(p[4], p[5]);
        unsigned a1 = cvtpk(p[2], p[3]),  b1 = cvtpk(p[6], p[7]);
        swap32(a0, b0); swap32(a1, b1);
        const bf8 pf0 = mk_bf8w(a0, a1, b0, b1);
        unsigned a2 = cvtpk(p[8], p[9]),   b2 = cvtpk(p[12], p[13]);
        unsigned a3 = cvtpk(p[10], p[11]), b3 = cvtpk(p[14], p[15]);
        swap32(a2, b2); swap32(a3, b3);
        const bf8 pf1 = mk_bf8w(a2, a3, b2, b3);

        // ---- PV swapped: O^T[d][q] += V^T x P, single 8-MFMA cluster ----
        asm volatile("s_waitcnt lgkmcnt(0)");
        __builtin_amdgcn_sched_barrier(0);
        __builtin_amdgcn_s_setprio(1);
#pragma unroll
        for (int ks = 0; ks < 2; ++ks) {
            const bf8 pf = ks ? pf1 : pf0;
#pragma unroll
            for (int dt = 0; dt < 4; ++dt) {
                const bf8 vf = mk_bf8(vt_[ks][dt][0], vt_[ks][dt][1]);
                oa[dt] = __builtin_amdgcn_mfma_f32_32x32x16_bf16(vf, pf, oa[dt], 0, 0, 0);
            }
        }
        __builtin_amdgcn_s_setprio(0);

        // ---- write-late: next tile's staged regs -> LDS ----
        if (t + 1 < NT) stage_write(buf ^ 1);
    }

    // ---- epilogue: normalize, store fp32; lane owns q=r31, d=32dt+8rr+4hi+i ----
    const float inv = 1.0f / l_run;
    float* op = OUT + ((size_t)(bb * ST + qrow)) * (NH * DH) + hh * DH;
#pragma unroll
    for (int dt = 0; dt < 4; ++dt)
#pragma unroll
        for (int rr = 0; rr < 4; ++rr) {
            f32x4 st;
            st[0] = oa[dt][rr * 4 + 0] * inv;
            st[1] = oa[dt][rr * 4 + 1] * inv;
            st[2] = oa[dt][rr * 4 + 2] * inv;
            st[3] = oa[dt][rr * 4 + 3] * inv;
            *(f32x4*)(op + dt * 32 + rr * 8 + hi * 4) = st;
        }
}

extern "C" void kernel_launch(void* const* d_in, const int* in_sizes, int n_in,
                              void* d_out, int out_size, void* d_ws, size_t ws_size,
                              hipStream_t stream) {
    const float* q  = (const float*)d_in[0];
    const float* tk = (const float*)d_in[1];
    const float* tv = (const float*)d_in[2];
    const float* ck = (const float*)d_in[3];
    const float* cv = (const float*)d_in[4];
    const float* bp = (const float*)d_in[5];
    float* out = (float*)d_out;
    attn_fwd<<<dim3((ST / 128) * B_ * NH), 256, 0, stream>>>(q, tk, tv, ck, cv, bp, out);
}